// Round 1
// baseline (831.289 us; speedup 1.0000x reference)
//
#include <hip/hip_runtime.h>
#include <math.h>

// MoE top-2/8: route -> grouped GEMM1 (gelu) -> grouped GEMM2 (scale) -> combine
// Shapes fixed: N=8192 tokens, C=1024, H=4096, E=8.

#define NTOK 8192
#define CDIM 1024
#define HDIM 4096
#define NEXP 8
#define MAXTILES 136               // worst-case sum over experts of ceil(cnt/128)
#define MAXROWS (MAXTILES * 128)

typedef unsigned short u16;
typedef __attribute__((ext_vector_type(8))) _Float16 half8;
typedef __attribute__((ext_vector_type(4))) float f32x4;

__device__ __forceinline__ u16 f2h(float f) {
    union { _Float16 h; u16 u; } cv; cv.h = (_Float16)f; return cv.u;
}
// 16B-slot swizzle within a 128x32-elem (64B/row) tile; involution over 2 bits.
__device__ __forceinline__ int swz(int r) { return (r & 3) ^ ((r >> 2) & 3); }

__device__ __forceinline__ void gll16(const void* g, void* l) {
    __builtin_amdgcn_global_load_lds((__attribute__((address_space(1))) void*)(g),
                                     (__attribute__((address_space(3))) void*)(l),
                                     16, 0, 0);
}

// ---------------- routing: gate logits, top-2 softmax, bucket append, x->fp16
__global__ __launch_bounds__(256) void k_route(
    const float* __restrict__ x, const float* __restrict__ gw,
    const float* __restrict__ gb, u16* __restrict__ xh,
    float2* __restrict__ rtw, int* __restrict__ cnt, int* __restrict__ lists)
{
    int tid = threadIdx.x, lane = tid & 63, wid = tid >> 6;
    int tok = blockIdx.x * 4 + wid;
    const float* xr = x + (size_t)tok * CDIM;
    float a[NEXP];
#pragma unroll
    for (int e = 0; e < NEXP; e++) a[e] = 0.f;
#pragma unroll
    for (int j = 0; j < 4; j++) {
        int k0 = j * 256 + lane * 4;
        float4 xv = *reinterpret_cast<const float4*>(xr + k0);
        ushort4 hv;
        hv.x = f2h(xv.x); hv.y = f2h(xv.y); hv.z = f2h(xv.z); hv.w = f2h(xv.w);
        *reinterpret_cast<ushort4*>(xh + (size_t)tok * CDIM + k0) = hv;
        const float* gr = gw + (size_t)k0 * NEXP;
#pragma unroll
        for (int t = 0; t < 4; t++) {
            float xs = (t == 0) ? xv.x : (t == 1) ? xv.y : (t == 2) ? xv.z : xv.w;
            float4 g0 = *reinterpret_cast<const float4*>(gr + t * 8);
            float4 g1 = *reinterpret_cast<const float4*>(gr + t * 8 + 4);
            a[0] += xs * g0.x; a[1] += xs * g0.y; a[2] += xs * g0.z; a[3] += xs * g0.w;
            a[4] += xs * g1.x; a[5] += xs * g1.y; a[6] += xs * g1.z; a[7] += xs * g1.w;
        }
    }
#pragma unroll
    for (int ofs = 32; ofs >= 1; ofs >>= 1) {
#pragma unroll
        for (int e = 0; e < NEXP; e++) a[e] += __shfl_xor(a[e], ofs, 64);
    }
    if (lane == 0) {
#pragma unroll
        for (int e = 0; e < NEXP; e++) a[e] += gb[e];
        int i0 = 0; float v0 = a[0];
#pragma unroll
        for (int e = 1; e < NEXP; e++) if (a[e] > v0) { v0 = a[e]; i0 = e; }
        int i1 = -1; float v1 = -3.4e38f;
#pragma unroll
        for (int e = 0; e < NEXP; e++) if (e != i0 && a[e] > v1) { v1 = a[e]; i1 = e; }
        float t = expf(v1 - v0);
        float w0 = 1.f / (1.f + t);
        rtw[tok] = make_float2(w0, t * w0);
        int p0 = atomicAdd(&cnt[i0], 1);
        lists[i0 * NTOK + p0] = tok * 2;
        int p1 = atomicAdd(&cnt[i1], 1);
        lists[i1 * NTOK + p1] = tok * 2 + 1;
    }
}

// ---------------- weight transpose+convert: [R][S] fp32 -> [S][R] fp16
__global__ __launch_bounds__(256) void k_transpose(
    const float* __restrict__ src, u16* __restrict__ dst, int R, int S)
{
    __shared__ __align__(16) u16 tile[64][68];
    int e = blockIdx.z;
    const float* se = src + (size_t)e * R * S;
    u16* de = dst + (size_t)e * R * S;
    int c0 = blockIdx.x * 64, r0 = blockIdx.y * 64;
    int tid = threadIdx.x;
    int rr = tid >> 4, cc = (tid & 15) * 4;
#pragma unroll
    for (int i = 0; i < 4; i++) {
        int r = rr + i * 16;
        float4 v = *reinterpret_cast<const float4*>(se + (size_t)(r0 + r) * S + c0 + cc);
        ushort4 hv; hv.x = f2h(v.x); hv.y = f2h(v.y); hv.z = f2h(v.z); hv.w = f2h(v.w);
        *reinterpret_cast<ushort4*>(&tile[r][cc]) = hv;
    }
    __syncthreads();
#pragma unroll
    for (int i = 0; i < 4; i++) {
        int row = rr + i * 16;
        ushort4 o;
        o.x = tile[cc + 0][row]; o.y = tile[cc + 1][row];
        o.z = tile[cc + 2][row]; o.w = tile[cc + 3][row];
        *reinterpret_cast<ushort4*>(de + (size_t)(c0 + row) * R + r0 + cc) = o;
    }
}

// ---------------- schedule: prefix sums, tile tables, pad lists, pair arrays
__global__ __launch_bounds__(256) void k_sched(
    int* __restrict__ ctrl, int* __restrict__ lists,
    const float2* __restrict__ rtw, int* __restrict__ ptok, float* __restrict__ pw)
{
    __shared__ int scnt[NEXP], stile[NEXP], sprow[NEXP], sstart[NEXP], stot;
    int tid = threadIdx.x;
    if (tid == 0) {
        int at = 0, ar = 0;
        for (int e = 0; e < NEXP; e++) {
            int c = ctrl[8 + e]; scnt[e] = c;
            int ti = (c + 127) >> 7;
            stile[e] = ti; sstart[e] = at; sprow[e] = ar;
            ctrl[16 + e] = ar;
            at += ti; ar += ti * 128;
        }
        stot = at; ctrl[0] = at;
    }
    __syncthreads();
    for (int t = tid; t < stot; t += 256) {
        int e = 0;
        while (e < NEXP - 1 && t >= sstart[e] + stile[e]) e++;
        ctrl[32 + t] = e;
        ctrl[32 + MAXTILES + t] = t - sstart[e];
    }
    for (int e = 0; e < NEXP; e++) {
        int c = scnt[e], lim = stile[e] * 128;
        if (c > 0) {
            int fill = lists[e * NTOK];
            for (int p = c + tid; p < lim; p += 256) lists[e * NTOK + p] = fill;
        }
    }
    __syncthreads();
    for (int e = 0; e < NEXP; e++) {
        int lim = stile[e] * 128;
        for (int p = tid; p < lim; p += 256) {
            int entry = lists[e * NTOK + p];
            int g = sprow[e] + p;
            ptok[g] = entry;
            float2 w = rtw[entry >> 1];
            pw[g] = (entry & 1) ? w.y : w.x;
        }
    }
}

// ---------------- grouped GEMM1: h = gelu(x[tok] @ w1[e] + b1[e])  (fp16 out)
__global__ __launch_bounds__(256) void k_ffn1(
    const u16* __restrict__ xh, const u16* __restrict__ w1t,
    const float* __restrict__ b1, u16* __restrict__ hbuf,
    const int* __restrict__ ctrl, const int* __restrict__ lists)
{
    __shared__ __align__(16) u16 As[2][128 * 32];
    __shared__ __align__(16) u16 Bs[2][128 * 32];
    int t = blockIdx.x;
    if (t >= ctrl[0]) return;
    int e = ctrl[32 + t];
    int rt = ctrl[32 + MAXTILES + t];
    int prow = ctrl[16 + e];
    int n0 = blockIdx.y * 128;
    int tid = threadIdx.x, lane = tid & 63, wid = tid >> 6;
    int cl = lane & 3;
    int r0 = wid * 32 + (lane >> 2);
    int r1 = r0 + 16;
    int tok0 = lists[e * NTOK + rt * 128 + r0] >> 1;
    int tok1 = lists[e * NTOK + rt * 128 + r1] >> 1;
    const u16* ag0 = xh + (size_t)tok0 * CDIM + (cl ^ swz(r0)) * 8;
    const u16* ag1 = xh + (size_t)tok1 * CDIM + (cl ^ swz(r1)) * 8;
    const u16* wb = w1t + (size_t)e * HDIM * CDIM + (size_t)n0 * CDIM;
    const u16* bg0 = wb + (size_t)r0 * CDIM + (cl ^ swz(r0)) * 8;
    const u16* bg1 = wb + (size_t)r1 * CDIM + (cl ^ swz(r1)) * 8;
    int wm = wid >> 1, wn = wid & 1;
    f32x4 acc[4][4];
#pragma unroll
    for (int m = 0; m < 4; m++)
#pragma unroll
        for (int n = 0; n < 4; n++) acc[m][n] = f32x4{0.f, 0.f, 0.f, 0.f};
    {
        u16* ad = &As[0][wid * 32 * 32];
        u16* bd = &Bs[0][wid * 32 * 32];
        gll16(ag0, ad); gll16(ag1, ad + 16 * 32);
        gll16(bg0, bd); gll16(bg1, bd + 16 * 32);
    }
    __syncthreads();
    const int nk = CDIM / 32;
    for (int s = 0; s < nk; s++) {
        int cur = s & 1;
        if (s + 1 < nk) {
            int k0 = (s + 1) * 32;
            u16* ad = &As[cur ^ 1][wid * 32 * 32];
            u16* bd = &Bs[cur ^ 1][wid * 32 * 32];
            gll16(ag0 + k0, ad); gll16(ag1 + k0, ad + 16 * 32);
            gll16(bg0 + k0, bd); gll16(bg1 + k0, bd + 16 * 32);
        }
        half8 af[4], bfv[4];
#pragma unroll
        for (int m = 0; m < 4; m++) {
            int r = wm * 64 + m * 16 + (lane & 15);
            af[m] = *reinterpret_cast<const half8*>(&As[cur][r * 32 + ((lane >> 4) ^ swz(r)) * 8]);
        }
#pragma unroll
        for (int n = 0; n < 4; n++) {
            int r = wn * 64 + n * 16 + (lane & 15);
            bfv[n] = *reinterpret_cast<const half8*>(&Bs[cur][r * 32 + ((lane >> 4) ^ swz(r)) * 8]);
        }
#pragma unroll
        for (int m = 0; m < 4; m++)
#pragma unroll
            for (int n = 0; n < 4; n++)
                acc[m][n] = __builtin_amdgcn_mfma_f32_16x16x32_f16(af[m], bfv[n], acc[m][n], 0, 0, 0);
        __syncthreads();
    }
#pragma unroll
    for (int m = 0; m < 4; m++) {
#pragma unroll
        for (int j = 0; j < 4; j++) {
            int p = rt * 128 + wm * 64 + m * 16 + (lane >> 4) * 4 + j;
            size_t hrow = (size_t)(prow + p) * HDIM;
#pragma unroll
            for (int n = 0; n < 4; n++) {
                int col = n0 + wn * 64 + n * 16 + (lane & 15);
                float v = acc[m][n][j] + b1[e * HDIM + col];
                float g = 0.5f * v * (1.f + erff(v * 0.70710678118654752f));
                hbuf[hrow + col] = f2h(g);
            }
        }
    }
}

// ---------------- grouped GEMM2: y = (h @ w2[e] + b2[e]) * gate_w -> ybuf[slot]
__global__ __launch_bounds__(256) void k_ffn2(
    const u16* __restrict__ hbuf, const u16* __restrict__ w2t,
    const float* __restrict__ b2, float* __restrict__ ybuf,
    const int* __restrict__ ctrl, const int* __restrict__ ptok,
    const float* __restrict__ pw)
{
    __shared__ __align__(16) u16 As[2][128 * 32];
    __shared__ __align__(16) u16 Bs[2][128 * 32];
    int t = blockIdx.x;
    if (t >= ctrl[0]) return;
    int e = ctrl[32 + t];
    int rt = ctrl[32 + MAXTILES + t];
    int prow = ctrl[16 + e];
    int cnte = ctrl[8 + e];
    int n0 = blockIdx.y * 128;
    int tid = threadIdx.x, lane = tid & 63, wid = tid >> 6;
    int cl = lane & 3;
    int r0 = wid * 32 + (lane >> 2);
    int r1 = r0 + 16;
    const u16* ag0 = hbuf + (size_t)(prow + rt * 128 + r0) * HDIM + (cl ^ swz(r0)) * 8;
    const u16* ag1 = hbuf + (size_t)(prow + rt * 128 + r1) * HDIM + (cl ^ swz(r1)) * 8;
    const u16* wb = w2t + (size_t)e * CDIM * HDIM + (size_t)n0 * HDIM;
    const u16* bg0 = wb + (size_t)r0 * HDIM + (cl ^ swz(r0)) * 8;
    const u16* bg1 = wb + (size_t)r1 * HDIM + (cl ^ swz(r1)) * 8;
    int wm = wid >> 1, wn = wid & 1;
    f32x4 acc[4][4];
#pragma unroll
    for (int m = 0; m < 4; m++)
#pragma unroll
        for (int n = 0; n < 4; n++) acc[m][n] = f32x4{0.f, 0.f, 0.f, 0.f};
    {
        u16* ad = &As[0][wid * 32 * 32];
        u16* bd = &Bs[0][wid * 32 * 32];
        gll16(ag0, ad); gll16(ag1, ad + 16 * 32);
        gll16(bg0, bd); gll16(bg1, bd + 16 * 32);
    }
    __syncthreads();
    const int nk = HDIM / 32;
    for (int s = 0; s < nk; s++) {
        int cur = s & 1;
        if (s + 1 < nk) {
            int k0 = (s + 1) * 32;
            u16* ad = &As[cur ^ 1][wid * 32 * 32];
            u16* bd = &Bs[cur ^ 1][wid * 32 * 32];
            gll16(ag0 + k0, ad); gll16(ag1 + k0, ad + 16 * 32);
            gll16(bg0 + k0, bd); gll16(bg1 + k0, bd + 16 * 32);
        }
        half8 af[4], bfv[4];
#pragma unroll
        for (int m = 0; m < 4; m++) {
            int r = wm * 64 + m * 16 + (lane & 15);
            af[m] = *reinterpret_cast<const half8*>(&As[cur][r * 32 + ((lane >> 4) ^ swz(r)) * 8]);
        }
#pragma unroll
        for (int n = 0; n < 4; n++) {
            int r = wn * 64 + n * 16 + (lane & 15);
            bfv[n] = *reinterpret_cast<const half8*>(&Bs[cur][r * 32 + ((lane >> 4) ^ swz(r)) * 8]);
        }
#pragma unroll
        for (int m = 0; m < 4; m++)
#pragma unroll
            for (int n = 0; n < 4; n++)
                acc[m][n] = __builtin_amdgcn_mfma_f32_16x16x32_f16(af[m], bfv[n], acc[m][n], 0, 0, 0);
        __syncthreads();
    }
#pragma unroll
    for (int m = 0; m < 4; m++) {
#pragma unroll
        for (int j = 0; j < 4; j++) {
            int p = rt * 128 + wm * 64 + m * 16 + (lane >> 4) * 4 + j;
            bool valid = p < cnte;
            int g = prow + p;
            int entry = ptok[g];
            float wgt = pw[g];
            int tok2 = entry >> 1, slot = entry & 1;
            float* yb = ybuf + ((size_t)slot * NTOK + (size_t)tok2) * CDIM;
#pragma unroll
            for (int n = 0; n < 4; n++) {
                int col = n0 + wn * 64 + n * 16 + (lane & 15);
                float v = acc[m][n][j] + b2[e * CDIM + col];
                if (valid) yb[col] = wgt * v;
            }
        }
    }
}

// ---------------- combine: out = ybuf[slot0] + ybuf[slot1]
__global__ __launch_bounds__(256) void k_combine(
    const float* __restrict__ ybuf, float* __restrict__ out)
{
    size_t i = (size_t)blockIdx.x * 256 + threadIdx.x;
    const float4* y0 = reinterpret_cast<const float4*>(ybuf);
    const float4* y1 = reinterpret_cast<const float4*>(ybuf + (size_t)NTOK * CDIM);
    float4 a = y0[i], b = y1[i];
    float4 o; o.x = a.x + b.x; o.y = a.y + b.y; o.z = a.z + b.z; o.w = a.w + b.w;
    reinterpret_cast<float4*>(out)[i] = o;
}

extern "C" void kernel_launch(void* const* d_in, const int* in_sizes, int n_in,
                              void* d_out, int out_size, void* d_ws, size_t ws_size,
                              hipStream_t stream)
{
    const float* x  = (const float*)d_in[0];
    const float* gw = (const float*)d_in[1];
    const float* gb = (const float*)d_in[2];
    const float* w1 = (const float*)d_in[3];
    const float* b1 = (const float*)d_in[4];
    const float* w2 = (const float*)d_in[5];
    const float* b2 = (const float*)d_in[6];
    float* out = (float*)d_out;
    char* ws = (char*)d_ws;

    size_t off = 0;
    int*    ctrl  = (int*)(ws + off);    off += 4096;
    float2* rtw   = (float2*)(ws + off); off += (size_t)NTOK * 8;
    int*    ptok  = (int*)(ws + off);    off += (size_t)MAXROWS * 4;
    float*  pw    = (float*)(ws + off);  off += (size_t)MAXROWS * 4;
    int*    lists = (int*)(ws + off);    off += (size_t)NEXP * NTOK * 4;
    u16*    xh    = (u16*)(ws + off);    off += (size_t)NTOK * CDIM * 2;
    u16*    w1t   = (u16*)(ws + off);    off += (size_t)NEXP * CDIM * HDIM * 2;
    u16*    w2t   = (u16*)(ws + off);    off += (size_t)NEXP * CDIM * HDIM * 2;
    u16*    hbuf  = (u16*)(ws + off);    off += (size_t)MAXROWS * HDIM * 2;
    float*  ybuf  = (float*)(ws + off);  off += (size_t)2 * NTOK * CDIM * 4;
    (void)ws_size; (void)in_sizes; (void)n_in; (void)out_size;

    hipMemsetAsync(ctrl + 8, 0, NEXP * sizeof(int), stream);
    k_route<<<dim3(NTOK / 4), 256, 0, stream>>>(x, gw, gb, xh, rtw, ctrl + 8, lists);
    k_transpose<<<dim3(HDIM / 64, CDIM / 64, NEXP), 256, 0, stream>>>(w1, w1t, CDIM, HDIM);
    k_transpose<<<dim3(CDIM / 64, HDIM / 64, NEXP), 256, 0, stream>>>(w2, w2t, HDIM, CDIM);
    k_sched<<<dim3(1), 256, 0, stream>>>(ctrl, lists, rtw, ptok, pw);
    k_ffn1<<<dim3(MAXTILES, HDIM / 128), 256, 0, stream>>>(xh, w1t, b1, hbuf, ctrl, lists);
    k_ffn2<<<dim3(MAXTILES, CDIM / 128), 256, 0, stream>>>(hbuf, w2t, b2, ybuf, ctrl, ptok, pw);
    k_combine<<<dim3(NTOK * CDIM / 1024), 256, 0, stream>>>(ybuf, out);
}

// Round 2
// 766.893 us; speedup vs baseline: 1.0840x; 1.0840x over previous
//
#include <hip/hip_runtime.h>
#include <math.h>

// MoE top-2/8: route -> grouped GEMM1 (gelu) -> grouped GEMM2 (scale, K-split) -> combine
// Shapes fixed: N=8192 tokens, C=1024, H=4096, E=8.
// FFN GEMMs: 256x256 tile, BK=64, 8 waves, 8-phase counted-vmcnt schedule (m201 template).

#define NTOK 8192
#define CDIM 1024
#define HDIM 4096
#define NEXP 8
#define MAXT2 71                   // worst-case sum over experts of ceil(cnt/256)
#define MAXROWS2 (MAXT2 * 256)

typedef unsigned short u16;
typedef __attribute__((ext_vector_type(8))) _Float16 half8;
typedef __attribute__((ext_vector_type(4))) float f32x4;

__device__ __forceinline__ u16 f2h(float f) {
    union { _Float16 h; u16 u; } cv; cv.h = (_Float16)f; return cv.u;
}
__device__ __forceinline__ void gll16(const u16* g, u16* l) {
    __builtin_amdgcn_global_load_lds((__attribute__((address_space(1))) void*)(g),
                                     (__attribute__((address_space(3))) void*)(l),
                                     16, 0, 0);
}

// ---------------- routing: gate logits, top-2 softmax, bucket append, x->fp16
__global__ __launch_bounds__(256) void k_route(
    const float* __restrict__ x, const float* __restrict__ gw,
    const float* __restrict__ gb, u16* __restrict__ xh,
    float2* __restrict__ rtw, int* __restrict__ cnt, int* __restrict__ lists)
{
    int tid = threadIdx.x, lane = tid & 63, wid = tid >> 6;
    int tok = blockIdx.x * 4 + wid;
    const float* xr = x + (size_t)tok * CDIM;
    float a[NEXP];
#pragma unroll
    for (int e = 0; e < NEXP; e++) a[e] = 0.f;
#pragma unroll
    for (int j = 0; j < 4; j++) {
        int k0 = j * 256 + lane * 4;
        float4 xv = *reinterpret_cast<const float4*>(xr + k0);
        ushort4 hv;
        hv.x = f2h(xv.x); hv.y = f2h(xv.y); hv.z = f2h(xv.z); hv.w = f2h(xv.w);
        *reinterpret_cast<ushort4*>(xh + (size_t)tok * CDIM + k0) = hv;
        const float* gr = gw + (size_t)k0 * NEXP;
#pragma unroll
        for (int t = 0; t < 4; t++) {
            float xs = (t == 0) ? xv.x : (t == 1) ? xv.y : (t == 2) ? xv.z : xv.w;
            float4 g0 = *reinterpret_cast<const float4*>(gr + t * 8);
            float4 g1 = *reinterpret_cast<const float4*>(gr + t * 8 + 4);
            a[0] += xs * g0.x; a[1] += xs * g0.y; a[2] += xs * g0.z; a[3] += xs * g0.w;
            a[4] += xs * g1.x; a[5] += xs * g1.y; a[6] += xs * g1.z; a[7] += xs * g1.w;
        }
    }
#pragma unroll
    for (int ofs = 32; ofs >= 1; ofs >>= 1) {
#pragma unroll
        for (int e = 0; e < NEXP; e++) a[e] += __shfl_xor(a[e], ofs, 64);
    }
    if (lane == 0) {
#pragma unroll
        for (int e = 0; e < NEXP; e++) a[e] += gb[e];
        int i0 = 0; float v0 = a[0];
#pragma unroll
        for (int e = 1; e < NEXP; e++) if (a[e] > v0) { v0 = a[e]; i0 = e; }
        int i1 = -1; float v1 = -3.4e38f;
#pragma unroll
        for (int e = 0; e < NEXP; e++) if (e != i0 && a[e] > v1) { v1 = a[e]; i1 = e; }
        float t = expf(v1 - v0);
        float w0 = 1.f / (1.f + t);
        rtw[tok] = make_float2(w0, t * w0);
        int p0 = atomicAdd(&cnt[i0], 1);
        lists[i0 * NTOK + p0] = tok * 2;
        int p1 = atomicAdd(&cnt[i1], 1);
        lists[i1 * NTOK + p1] = tok * 2 + 1;
    }
}

// ---------------- weight transpose+convert: [R][S] fp32 -> [S][R] fp16
__global__ __launch_bounds__(256) void k_transpose(
    const float* __restrict__ src, u16* __restrict__ dst, int R, int S)
{
    __shared__ __align__(16) u16 tile[64][68];
    int e = blockIdx.z;
    const float* se = src + (size_t)e * R * S;
    u16* de = dst + (size_t)e * R * S;
    int c0 = blockIdx.x * 64, r0 = blockIdx.y * 64;
    int tid = threadIdx.x;
    int rr = tid >> 4, cc = (tid & 15) * 4;
#pragma unroll
    for (int i = 0; i < 4; i++) {
        int r = rr + i * 16;
        float4 v = *reinterpret_cast<const float4*>(se + (size_t)(r0 + r) * S + c0 + cc);
        ushort4 hv; hv.x = f2h(v.x); hv.y = f2h(v.y); hv.z = f2h(v.z); hv.w = f2h(v.w);
        *reinterpret_cast<ushort4*>(&tile[r][cc]) = hv;
    }
    __syncthreads();
#pragma unroll
    for (int i = 0; i < 4; i++) {
        int row = rr + i * 16;
        ushort4 o;
        o.x = tile[cc + 0][row]; o.y = tile[cc + 1][row];
        o.z = tile[cc + 2][row]; o.w = tile[cc + 3][row];
        *reinterpret_cast<ushort4*>(de + (size_t)(c0 + row) * R + r0 + cc) = o;
    }
}

// ---------------- schedule: prefix sums, tile tables (256-granularity), pad lists
__global__ __launch_bounds__(256) void k_sched(
    int* __restrict__ ctrl, int* __restrict__ lists,
    const float2* __restrict__ rtw, int* __restrict__ ptok, float* __restrict__ pw)
{
    __shared__ int scnt[NEXP], stile[NEXP], sprow[NEXP], sstart[NEXP], stot;
    int tid = threadIdx.x;
    if (tid == 0) {
        int at = 0, ar = 0;
        for (int e = 0; e < NEXP; e++) {
            int c = ctrl[8 + e]; scnt[e] = c;
            int ti = (c + 255) >> 8;
            stile[e] = ti; sstart[e] = at; sprow[e] = ar;
            ctrl[16 + e] = ar;
            at += ti; ar += ti * 256;
        }
        stot = at; ctrl[0] = at;
    }
    __syncthreads();
    for (int t = tid; t < stot; t += 256) {
        int e = 0;
        while (e < NEXP - 1 && t >= sstart[e] + stile[e]) e++;
        ctrl[32 + t] = e;
        ctrl[32 + MAXT2 + t] = t - sstart[e];
    }
    for (int e = 0; e < NEXP; e++) {
        int c = scnt[e], lim = stile[e] * 256;
        if (c > 0) {
            int fill = lists[e * NTOK];
            for (int p = c + tid; p < lim; p += 256) lists[e * NTOK + p] = fill;
        }
    }
    __syncthreads();
    for (int e = 0; e < NEXP; e++) {
        int lim = stile[e] * 256;
        for (int p = tid; p < lim; p += 256) {
            int entry = lists[e * NTOK + p];
            int g = sprow[e] + p;
            ptok[g] = entry;
            float2 w = rtw[entry >> 1];
            pw[g] = (entry & 1) ? w.y : w.x;
        }
    }
}

// ======== 8-phase 256x256 GEMM engine (macros; rely on local names in scope) ====
// LDS: Ab/Bb = [2 bufs][256 rows][64 k] fp16 each (32KB*4 = 128KB dynamic).
// Swizzle: 16B chunk slot' = slot ^ (row&7); staged via inverse-swizzled global src.
#define FFN_DSLOAD_A(BUF, QR) do { \
    _Pragma("unroll") for (int fm_ = 0; fm_ < 4; ++fm_) { \
        int rb_ = ((wm * 128) + ((QR) * 4 + fm_) * 16) * 64 + (BUF) * 16384; \
        af[fm_][0] = *reinterpret_cast<const half8*>(&Ab[rb_ + offK0]); \
        af[fm_][1] = *reinterpret_cast<const half8*>(&Ab[rb_ + offK1]); \
    } } while (0)

#define FFN_DSLOAD_B(BUF, QC) do { \
    _Pragma("unroll") for (int fn_ = 0; fn_ < 2; ++fn_) { \
        int rb_ = ((wn * 64) + ((QC) * 2 + fn_) * 16) * 64 + (BUF) * 16384; \
        bf[QC][fn_][0] = *reinterpret_cast<const half8*>(&Bb[rb_ + offK0]); \
        bf[QC][fn_][1] = *reinterpret_cast<const half8*>(&Bb[rb_ + offK1]); \
    } } while (0)

#define FFN_MFMA(QR, QC) do { \
    __builtin_amdgcn_s_setprio(1); \
    _Pragma("unroll") for (int fm_ = 0; fm_ < 4; ++fm_) \
    _Pragma("unroll") for (int fn_ = 0; fn_ < 2; ++fn_) { \
        acc[(QR) * 4 + fm_][(QC) * 2 + fn_] = __builtin_amdgcn_mfma_f32_16x16x32_f16( \
            bf[QC][fn_][0], af[fm_][0], acc[(QR) * 4 + fm_][(QC) * 2 + fn_], 0, 0, 0); \
        acc[(QR) * 4 + fm_][(QC) * 2 + fn_] = __builtin_amdgcn_mfma_f32_16x16x32_f16( \
            bf[QC][fn_][1], af[fm_][1], acc[(QR) * 4 + fm_][(QC) * 2 + fn_], 0, 0, 0); \
    } \
    __builtin_amdgcn_s_setprio(0); } while (0)

#define FFN_BAR() do { __builtin_amdgcn_sched_barrier(0); \
    __builtin_amdgcn_s_barrier(); __builtin_amdgcn_sched_barrier(0); } while (0)

#define FFN_VMW4() asm volatile("s_waitcnt vmcnt(4)" ::: "memory")

#define FFN_STAGE_A(BUF, H, KT) do { \
    gll16(aptr[H][0] + (size_t)(KT) * 64, &Ab[(BUF) * 16384 + ((H) * 128 + wv * 16) * 64]); \
    gll16(aptr[H][1] + (size_t)(KT) * 64, &Ab[(BUF) * 16384 + ((H) * 128 + wv * 16 + 8) * 64]); } while (0)

#define FFN_STAGE_B(BUF, H, KT) do { \
    gll16(bptr[H][0] + (size_t)(KT) * 64, &Bb[(BUF) * 16384 + ((H) * 128 + wv * 16) * 64]); \
    gll16(bptr[H][1] + (size_t)(KT) * 64, &Bb[(BUF) * 16384 + ((H) * 128 + wv * 16 + 8) * 64]); } while (0)

// stages/iter: p0,p1=A buf1 (tile 2i+1); p2,p3=B buf0 (2i+2); p4,p5=A buf0 (2i+2);
// p6,p7=B buf1 (2i+3). vmcnt(4) BEFORE barrier2 of p3/p7 publishes all but last 2 halves.
#define FFN_KLOOP(NK) do { \
    FFN_STAGE_B(0, 0, 0); FFN_STAGE_B(0, 1, 0); \
    FFN_STAGE_A(0, 0, 0); FFN_STAGE_A(0, 1, 0); \
    FFN_STAGE_B(1, 0, 1); FFN_STAGE_B(1, 1, 1); \
    FFN_VMW4(); FFN_BAR(); \
    for (int i_ = 0; i_ < (NK) / 2; ++i_) { \
        int k1_ = 2 * i_ + 1; \
        int k2_ = (2 * i_ + 2 < (NK)) ? 2 * i_ + 2 : (NK) - 1; \
        int k3_ = (2 * i_ + 3 < (NK)) ? 2 * i_ + 3 : (NK) - 1; \
        FFN_DSLOAD_A(0, 0); FFN_DSLOAD_B(0, 0); FFN_STAGE_A(1, 0, k1_); FFN_BAR(); FFN_MFMA(0, 0); FFN_BAR(); \
        FFN_DSLOAD_B(0, 1); FFN_STAGE_A(1, 1, k1_); FFN_BAR(); FFN_MFMA(0, 1); FFN_BAR(); \
        FFN_DSLOAD_A(0, 1); FFN_STAGE_B(0, 0, k2_); FFN_BAR(); FFN_MFMA(1, 0); FFN_BAR(); \
        FFN_STAGE_B(0, 1, k2_); FFN_BAR(); FFN_MFMA(1, 1); FFN_VMW4(); FFN_BAR(); \
        FFN_DSLOAD_A(1, 0); FFN_DSLOAD_B(1, 0); FFN_STAGE_A(0, 0, k2_); FFN_BAR(); FFN_MFMA(0, 0); FFN_BAR(); \
        FFN_DSLOAD_B(1, 1); FFN_STAGE_A(0, 1, k2_); FFN_BAR(); FFN_MFMA(0, 1); FFN_BAR(); \
        FFN_DSLOAD_A(1, 1); FFN_STAGE_B(1, 0, k3_); FFN_BAR(); FFN_MFMA(1, 0); FFN_BAR(); \
        FFN_STAGE_B(1, 1, k3_); FFN_BAR(); FFN_MFMA(1, 1); FFN_VMW4(); FFN_BAR(); \
    } } while (0)

// ---------------- grouped GEMM1: h = gelu(x[tok] @ w1[e] + b1[e])  (fp16 out)
__global__ __launch_bounds__(512, 2) void k_ffn1(
    const u16* __restrict__ xh, const u16* __restrict__ w1t,
    const float* __restrict__ b1, u16* __restrict__ hbuf,
    const int* __restrict__ ctrl, const int* __restrict__ lists)
{
    extern __shared__ u16 lds[];
    u16* Ab = lds;                 // [2][256*64]
    u16* Bb = lds + 2 * 256 * 64;  // [2][256*64]
    int nwg = gridDim.x * gridDim.y;                   // 71*16=1136, %8==0
    int lid = blockIdx.y * gridDim.x + blockIdx.x;
    int sl = (lid & 7) * (nwg >> 3) + (lid >> 3);      // XCD-chunked bijection
    int t = sl % gridDim.x;
    int by = sl / gridDim.x;
    if (t >= ctrl[0]) return;
    int e = ctrl[32 + t], rt = ctrl[32 + MAXT2 + t], prow = ctrl[16 + e];
    int n0 = by * 256;
    int tid = threadIdx.x, lane = tid & 63, wv = tid >> 6;
    int wm = wv >> 2, wn = wv & 3;
    int lr = lane >> 3;
    int chunk = (lane & 7) ^ lr;                       // inverse-swizzled global src
    const int* lrow = lists + e * NTOK + rt * 256;
    const u16* aptr[2][2]; const u16* bptr[2][2];
#pragma unroll
    for (int h = 0; h < 2; ++h)
#pragma unroll
        for (int g = 0; g < 2; ++g) {
            int r = h * 128 + wv * 16 + g * 8 + lr;
            int tok = lrow[r] >> 1;
            aptr[h][g] = xh + (size_t)tok * CDIM + chunk * 8;
            bptr[h][g] = w1t + (size_t)e * HDIM * CDIM + (size_t)(n0 + r) * CDIM + chunk * 8;
        }
    int offK0 = (lane & 15) * 64 + (((lane >> 4) ^ (lane & 7)) * 8);
    int offK1 = (lane & 15) * 64 + ((((lane >> 4) + 4) ^ (lane & 7)) * 8);
    f32x4 acc[8][4];
#pragma unroll
    for (int m = 0; m < 8; ++m)
#pragma unroll
        for (int n = 0; n < 4; ++n) acc[m][n] = f32x4{0.f, 0.f, 0.f, 0.f};
    half8 af[4][2], bf[2][2][2];

    FFN_KLOOP(16);   // K = 1024 = 16 tiles of 64

    // epilogue: D row=(lane>>4)*4+j -> hbuf col; D col=lane&15 -> token row
    const f32x4* b1v = reinterpret_cast<const f32x4*>(b1 + (size_t)e * HDIM);
    f32x4 bv[4];
#pragma unroll
    for (int n = 0; n < 4; ++n)
        bv[n] = b1v[(n0 + wn * 64 + n * 16) / 4 + (lane >> 4)];
#pragma unroll
    for (int m = 0; m < 8; ++m) {
        int grow = prow + rt * 256 + wm * 128 + m * 16 + (lane & 15);
        u16* hr = hbuf + (size_t)grow * HDIM + n0 + wn * 64 + (lane >> 4) * 4;
#pragma unroll
        for (int n = 0; n < 4; ++n) {
            ushort4 o;
#pragma unroll
            for (int j = 0; j < 4; ++j) {
                float v = acc[m][n][j] + bv[n][j];
                float gl = 0.5f * v * (1.f + erff(v * 0.70710678118654752f));
                ((u16*)&o)[j] = f2h(gl);
            }
            *reinterpret_cast<ushort4*>(hr + n * 16) = o;
        }
    }
}

// ---------------- grouped GEMM2 (K-split x2): y = (h @ w2[e] [+ b2]) * gate_w
__global__ __launch_bounds__(512, 2) void k_ffn2(
    const u16* __restrict__ hbuf, const u16* __restrict__ w2t,
    const float* __restrict__ b2, float* __restrict__ ybuf,
    const int* __restrict__ ctrl, const int* __restrict__ ptok,
    const float* __restrict__ pw)
{
    extern __shared__ u16 lds[];
    u16* Ab = lds;
    u16* Bb = lds + 2 * 256 * 64;
    int nwg = gridDim.x * gridDim.y * gridDim.z;       // 71*4*2=568, %8==0
    int lid = ((int)blockIdx.z * gridDim.y + blockIdx.y) * gridDim.x + blockIdx.x;
    int sl = (lid & 7) * (nwg >> 3) + (lid >> 3);
    int t = sl % gridDim.x;
    int r2 = sl / gridDim.x;
    int by = r2 & 3, kh = r2 >> 2;
    if (t >= ctrl[0]) return;
    int e = ctrl[32 + t], rt = ctrl[32 + MAXT2 + t], prow = ctrl[16 + e];
    int n0 = by * 256;
    int tid = threadIdx.x, lane = tid & 63, wv = tid >> 6;
    int wm = wv >> 2, wn = wv & 3;
    int lr = lane >> 3;
    int chunk = (lane & 7) ^ lr;
    int rowbase = prow + rt * 256;
    const u16* aptr[2][2]; const u16* bptr[2][2];
#pragma unroll
    for (int h = 0; h < 2; ++h)
#pragma unroll
        for (int g = 0; g < 2; ++g) {
            int r = h * 128 + wv * 16 + g * 8 + lr;
            aptr[h][g] = hbuf + (size_t)(rowbase + r) * HDIM + kh * 2048 + chunk * 8;
            bptr[h][g] = w2t + (size_t)e * CDIM * HDIM + (size_t)(n0 + r) * HDIM + kh * 2048 + chunk * 8;
        }
    int offK0 = (lane & 15) * 64 + (((lane >> 4) ^ (lane & 7)) * 8);
    int offK1 = (lane & 15) * 64 + ((((lane >> 4) + 4) ^ (lane & 7)) * 8);
    f32x4 acc[8][4];
#pragma unroll
    for (int m = 0; m < 8; ++m)
#pragma unroll
        for (int n = 0; n < 4; ++n) acc[m][n] = f32x4{0.f, 0.f, 0.f, 0.f};
    half8 af[4][2], bf[2][2][2];

    FFN_KLOOP(32);   // K-half = 2048 = 32 tiles of 64

    int cnte = ctrl[8 + e];
    const f32x4* b2v = reinterpret_cast<const f32x4*>(b2 + (size_t)e * CDIM);
    f32x4 bv[4];
#pragma unroll
    for (int n = 0; n < 4; ++n)
        bv[n] = b2v[(n0 + wn * 64 + n * 16) / 4 + (lane >> 4)];
#pragma unroll
    for (int m = 0; m < 8; ++m) {
        int p = rt * 256 + wm * 128 + m * 16 + (lane & 15);
        bool valid = p < cnte;
        int g = prow + p;
        int entry = ptok[g];
        float wgt = pw[g];
        float* yb = ybuf + ((size_t)((entry & 1) * 2 + kh) * NTOK + (size_t)(entry >> 1)) * CDIM
                  + n0 + wn * 64 + (lane >> 4) * 4;
#pragma unroll
        for (int n = 0; n < 4; ++n) {
            f32x4 v = acc[m][n];
            if (kh == 0) v = v + bv[n];
            v = v * wgt;
            if (valid) *reinterpret_cast<f32x4*>(yb + n * 16) = v;
        }
    }
}

// ---------------- combine: out = sum of 4 ybuf slices (2 slots x 2 K-halves)
__global__ __launch_bounds__(256) void k_combine(
    const float* __restrict__ ybuf, float* __restrict__ out)
{
    size_t i = ((size_t)blockIdx.x * 256 + threadIdx.x) * 4;
    const size_t S = (size_t)NTOK * CDIM;
    f32x4 a = *reinterpret_cast<const f32x4*>(ybuf + i);
    f32x4 b = *reinterpret_cast<const f32x4*>(ybuf + S + i);
    f32x4 c = *reinterpret_cast<const f32x4*>(ybuf + 2 * S + i);
    f32x4 d = *reinterpret_cast<const f32x4*>(ybuf + 3 * S + i);
    *reinterpret_cast<f32x4*>(out + i) = (a + b) + (c + d);
}

extern "C" void kernel_launch(void* const* d_in, const int* in_sizes, int n_in,
                              void* d_out, int out_size, void* d_ws, size_t ws_size,
                              hipStream_t stream)
{
    const float* x  = (const float*)d_in[0];
    const float* gw = (const float*)d_in[1];
    const float* gb = (const float*)d_in[2];
    const float* w1 = (const float*)d_in[3];
    const float* b1 = (const float*)d_in[4];
    const float* w2 = (const float*)d_in[5];
    const float* b2 = (const float*)d_in[6];
    float* out = (float*)d_out;
    char* ws = (char*)d_ws;

    size_t off = 0;
    int*    ctrl  = (int*)(ws + off);    off += 4096;
    float2* rtw   = (float2*)(ws + off); off += (size_t)NTOK * 8;
    int*    ptok  = (int*)(ws + off);    off += (size_t)MAXROWS2 * 4;
    float*  pw    = (float*)(ws + off);  off += (size_t)MAXROWS2 * 4;
    int*    lists = (int*)(ws + off);    off += (size_t)NEXP * NTOK * 4;
    u16*    xh    = (u16*)(ws + off);    off += (size_t)NTOK * CDIM * 2;
    u16*    w1t   = (u16*)(ws + off);    off += (size_t)NEXP * CDIM * HDIM * 2;
    u16*    w2t   = (u16*)(ws + off);    off += (size_t)NEXP * CDIM * HDIM * 2;
    u16*    hbuf  = (u16*)(ws + off);    off += (size_t)MAXROWS2 * HDIM * 2;
    float*  ybuf  = (float*)(ws + off);  off += (size_t)4 * NTOK * CDIM * 4;
    (void)ws_size; (void)in_sizes; (void)n_in; (void)out_size;

    hipFuncSetAttribute((const void*)k_ffn1, hipFuncAttributeMaxDynamicSharedMemorySize, 131072);
    hipFuncSetAttribute((const void*)k_ffn2, hipFuncAttributeMaxDynamicSharedMemorySize, 131072);

    hipMemsetAsync(ctrl + 8, 0, NEXP * sizeof(int), stream);
    k_route<<<dim3(NTOK / 4), 256, 0, stream>>>(x, gw, gb, xh, rtw, ctrl + 8, lists);
    k_transpose<<<dim3(HDIM / 64, CDIM / 64, NEXP), 256, 0, stream>>>(w1, w1t, CDIM, HDIM);
    k_transpose<<<dim3(CDIM / 64, HDIM / 64, NEXP), 256, 0, stream>>>(w2, w2t, HDIM, CDIM);
    k_sched<<<dim3(1), 256, 0, stream>>>(ctrl, lists, rtw, ptok, pw);
    k_ffn1<<<dim3(MAXT2, HDIM / 256), 512, 131072, stream>>>(xh, w1t, b1, hbuf, ctrl, lists);
    k_ffn2<<<dim3(MAXT2, CDIM / 256, 2), 512, 131072, stream>>>(hbuf, w2t, b2, ybuf, ctrl, ptok, pw);
    k_combine<<<dim3(NTOK * CDIM / 1024), 256, 0, stream>>>(ybuf, out);
}

// Round 4
// 707.790 us; speedup vs baseline: 1.1745x; 1.0835x over previous
//
#include <hip/hip_runtime.h>
#include <math.h>

// MoE top-2/8: route -> grouped GEMM1 (gelu) -> grouped GEMM2 (scale, K-split) -> combine
// Shapes fixed: N=8192 tokens, C=1024, H=4096, E=8.
// FFN GEMMs: 256x256 tile, BK=64, 8 waves, 8-phase counted-vmcnt schedule (m201 template).
// R3 (resubmit after infra failure): half8-typed LDS reads (force ds_read_b128),
// pointer-bump staging, fast-erf GELU, parallel pair-fill kernel.

#define NTOK 8192
#define CDIM 1024
#define HDIM 4096
#define NEXP 8
#define MAXT2 71                   // worst-case sum over experts of ceil(cnt/256)
#define MAXROWS2 (MAXT2 * 256)

typedef unsigned short u16;
typedef __attribute__((ext_vector_type(8))) _Float16 half8;
typedef __attribute__((ext_vector_type(4))) float f32x4;

__device__ __forceinline__ u16 f2h(float f) {
    union { _Float16 h; u16 u; } cv; cv.h = (_Float16)f; return cv.u;
}
__device__ __forceinline__ void gll16(const u16* g, u16* l) {
    __builtin_amdgcn_global_load_lds((__attribute__((address_space(1))) void*)(g),
                                     (__attribute__((address_space(3))) void*)(l),
                                     16, 0, 0);
}
// exact-GELU via A&S 7.1.26 erf approx, |err(erf)| <= 1.5e-7
__device__ __forceinline__ float gelu_f(float v) {
    float u = 0.70710678118654752f * v;
    float au = fabsf(u);
    float t = __builtin_amdgcn_rcpf(1.0f + 0.3275911f * au);
    float p = t * (0.254829592f + t * (-0.284496736f + t * (1.421413741f +
              t * (-1.453152027f + t * 1.061405429f))));
    float ea = __expf(-au * au);
    float er = 1.0f - p * ea;
    er = (u < 0.f) ? -er : er;
    return 0.5f * v * (1.0f + er);
}

// ---------------- routing: gate logits, top-2 softmax, bucket append, x->fp16
__global__ __launch_bounds__(256) void k_route(
    const float* __restrict__ x, const float* __restrict__ gw,
    const float* __restrict__ gb, u16* __restrict__ xh,
    float2* __restrict__ rtw, int* __restrict__ cnt, int* __restrict__ lists)
{
    int tid = threadIdx.x, lane = tid & 63, wid = tid >> 6;
    int tok = blockIdx.x * 4 + wid;
    const float* xr = x + (size_t)tok * CDIM;
    float a[NEXP];
#pragma unroll
    for (int e = 0; e < NEXP; e++) a[e] = 0.f;
#pragma unroll
    for (int j = 0; j < 4; j++) {
        int k0 = j * 256 + lane * 4;
        float4 xv = *reinterpret_cast<const float4*>(xr + k0);
        ushort4 hv;
        hv.x = f2h(xv.x); hv.y = f2h(xv.y); hv.z = f2h(xv.z); hv.w = f2h(xv.w);
        *reinterpret_cast<ushort4*>(xh + (size_t)tok * CDIM + k0) = hv;
        const float* gr = gw + (size_t)k0 * NEXP;
#pragma unroll
        for (int t = 0; t < 4; t++) {
            float xs = (t == 0) ? xv.x : (t == 1) ? xv.y : (t == 2) ? xv.z : xv.w;
            float4 g0 = *reinterpret_cast<const float4*>(gr + t * 8);
            float4 g1 = *reinterpret_cast<const float4*>(gr + t * 8 + 4);
            a[0] += xs * g0.x; a[1] += xs * g0.y; a[2] += xs * g0.z; a[3] += xs * g0.w;
            a[4] += xs * g1.x; a[5] += xs * g1.y; a[6] += xs * g1.z; a[7] += xs * g1.w;
        }
    }
#pragma unroll
    for (int ofs = 32; ofs >= 1; ofs >>= 1) {
#pragma unroll
        for (int e = 0; e < NEXP; e++) a[e] += __shfl_xor(a[e], ofs, 64);
    }
    if (lane == 0) {
#pragma unroll
        for (int e = 0; e < NEXP; e++) a[e] += gb[e];
        int i0 = 0; float v0 = a[0];
#pragma unroll
        for (int e = 1; e < NEXP; e++) if (a[e] > v0) { v0 = a[e]; i0 = e; }
        int i1 = -1; float v1 = -3.4e38f;
#pragma unroll
        for (int e = 0; e < NEXP; e++) if (e != i0 && a[e] > v1) { v1 = a[e]; i1 = e; }
        float t = expf(v1 - v0);
        float w0 = 1.f / (1.f + t);
        rtw[tok] = make_float2(w0, t * w0);
        int p0 = atomicAdd(&cnt[i0], 1);
        lists[i0 * NTOK + p0] = tok * 2;
        int p1 = atomicAdd(&cnt[i1], 1);
        lists[i1 * NTOK + p1] = tok * 2 + 1;
    }
}

// ---------------- weight transpose+convert: [R][S] fp32 -> [S][R] fp16
__global__ __launch_bounds__(256) void k_transpose(
    const float* __restrict__ src, u16* __restrict__ dst, int R, int S)
{
    __shared__ __align__(16) u16 tile[64][68];
    int e = blockIdx.z;
    const float* se = src + (size_t)e * R * S;
    u16* de = dst + (size_t)e * R * S;
    int c0 = blockIdx.x * 64, r0 = blockIdx.y * 64;
    int tid = threadIdx.x;
    int rr = tid >> 4, cc = (tid & 15) * 4;
#pragma unroll
    for (int i = 0; i < 4; i++) {
        int r = rr + i * 16;
        float4 v = *reinterpret_cast<const float4*>(se + (size_t)(r0 + r) * S + c0 + cc);
        ushort4 hv; hv.x = f2h(v.x); hv.y = f2h(v.y); hv.z = f2h(v.z); hv.w = f2h(v.w);
        *reinterpret_cast<ushort4*>(&tile[r][cc]) = hv;
    }
    __syncthreads();
#pragma unroll
    for (int i = 0; i < 4; i++) {
        int row = rr + i * 16;
        ushort4 o;
        o.x = tile[cc + 0][row]; o.y = tile[cc + 1][row];
        o.z = tile[cc + 2][row]; o.w = tile[cc + 3][row];
        *reinterpret_cast<ushort4*>(de + (size_t)(c0 + row) * R + r0 + cc) = o;
    }
}

// ---------------- schedule: prefix sums, tile tables (256-granularity), pad lists
__global__ __launch_bounds__(256) void k_sched(
    int* __restrict__ ctrl, int* __restrict__ lists)
{
    __shared__ int scnt[NEXP], stile[NEXP], sstart[NEXP], stot;
    int tid = threadIdx.x;
    if (tid == 0) {
        int at = 0, ar = 0;
        for (int e = 0; e < NEXP; e++) {
            int c = ctrl[8 + e]; scnt[e] = c;
            int ti = (c + 255) >> 8;
            stile[e] = ti; sstart[e] = at;
            ctrl[16 + e] = ar;
            at += ti; ar += ti * 256;
        }
        stot = at; ctrl[0] = at; ctrl[1] = ar;
    }
    __syncthreads();
    for (int t = tid; t < stot; t += 256) {
        int e = 0;
        while (e < NEXP - 1 && t >= sstart[e] + stile[e]) e++;
        ctrl[32 + t] = e;
        ctrl[32 + MAXT2 + t] = t - sstart[e];
    }
    for (int e = 0; e < NEXP; e++) {
        int c = scnt[e], lim = stile[e] * 256;
        if (c > 0) {
            int fill = lists[e * NTOK];
            for (int p = c + tid; p < lim; p += 256) lists[e * NTOK + p] = fill;
        }
    }
}

// ---------------- pair arrays (parallel): ptok/pw for every padded row
__global__ __launch_bounds__(256) void k_pairs(
    const int* __restrict__ ctrl, const int* __restrict__ lists,
    const float2* __restrict__ rtw, int* __restrict__ ptok, float* __restrict__ pw)
{
    int tot = ctrl[1];
    for (int g = blockIdx.x * 256 + threadIdx.x; g < tot; g += gridDim.x * 256) {
        int e = 0;
#pragma unroll
        for (int q = 1; q < NEXP; q++) e = (g >= ctrl[16 + q]) ? q : e;
        int p = g - ctrl[16 + e];
        int entry = lists[e * NTOK + p];
        ptok[g] = entry;
        float2 w = rtw[entry >> 1];
        pw[g] = (entry & 1) ? w.y : w.x;
    }
}

// ======== 8-phase 256x256 GEMM engine (macros; use local names in scope) ========
// LDS: ldsA/ldsB = [2 bufs][256 rows][64 k] fp16 each (128KB total dynamic).
// Swizzle: 16B chunk slot' = slot ^ (row&7); staged via inverse-swizzled global src.
// All fragment reads are half8-typed (16B-aligned) -> ds_read_b128 offset:imm.
#define DSA(BUF, QR) do { \
    _Pragma("unroll") for (int fm_ = 0; fm_ < 4; ++fm_) { \
        af[fm_][0] = HA[aIdx0 + ((QR) * 4 + fm_) * 128 + (BUF) * 2048]; \
        af[fm_][1] = HA[aIdx1 + ((QR) * 4 + fm_) * 128 + (BUF) * 2048]; \
    } } while (0)

#define DSB(BUF, QC) do { \
    _Pragma("unroll") for (int fn_ = 0; fn_ < 2; ++fn_) { \
        bf[QC][fn_][0] = HB[bIdx0 + ((QC) * 2 + fn_) * 128 + (BUF) * 2048]; \
        bf[QC][fn_][1] = HB[bIdx1 + ((QC) * 2 + fn_) * 128 + (BUF) * 2048]; \
    } } while (0)

#define FFN_MFMA(QR, QC) do { \
    __builtin_amdgcn_s_setprio(1); \
    _Pragma("unroll") for (int fm_ = 0; fm_ < 4; ++fm_) \
    _Pragma("unroll") for (int fn_ = 0; fn_ < 2; ++fn_) { \
        acc[(QR) * 4 + fm_][(QC) * 2 + fn_] = __builtin_amdgcn_mfma_f32_16x16x32_f16( \
            bf[QC][fn_][0], af[fm_][0], acc[(QR) * 4 + fm_][(QC) * 2 + fn_], 0, 0, 0); \
        acc[(QR) * 4 + fm_][(QC) * 2 + fn_] = __builtin_amdgcn_mfma_f32_16x16x32_f16( \
            bf[QC][fn_][1], af[fm_][1], acc[(QR) * 4 + fm_][(QC) * 2 + fn_], 0, 0, 0); \
    } \
    __builtin_amdgcn_s_setprio(0); } while (0)

#define PUB() do { __builtin_amdgcn_sched_barrier(0); __builtin_amdgcn_s_barrier(); } while (0)
#define MST() do { asm volatile("s_waitcnt lgkmcnt(0)" ::: "memory"); \
                   __builtin_amdgcn_sched_barrier(0); } while (0)
#define VMW4() asm volatile("s_waitcnt vmcnt(4)" ::: "memory")

#define STA(BUF, H) do { \
    gll16(pa[H][0], ldsA + (BUF) * 16384 + ((H) * 128 + wv * 16) * 64); pa[H][0] += 64; \
    gll16(pa[H][1], ldsA + (BUF) * 16384 + ((H) * 128 + wv * 16 + 8) * 64); pa[H][1] += 64; } while (0)

#define STB(BUF, H) do { \
    gll16(pb[H][0], ldsB + (BUF) * 16384 + ((H) * 128 + wv * 16) * 64); pb[H][0] += 64; \
    gll16(pb[H][1], ldsB + (BUF) * 16384 + ((H) * 128 + wv * 16 + 8) * 64); pb[H][1] += 64; } while (0)

// per iteration: tiles (2i)->buf0, (2i+1)->buf1; stage A(2i+1),B(2i+2),A(2i+2),B(2i+3).
#define FFN_KLOOP(NK) do { \
    STB(0, 0); STB(0, 1); STA(0, 0); STA(0, 1); STB(1, 0); STB(1, 1); \
    VMW4(); PUB(); \
    for (int i_ = 0; i_ < (NK) / 2; ++i_) { \
        DSA(0, 0); DSB(0, 0); STA(1, 0);  PUB(); MST(); FFN_MFMA(0, 0); PUB(); \
        DSB(0, 1); STA(1, 1);             PUB(); MST(); FFN_MFMA(0, 1); PUB(); \
        DSA(0, 1); STB(0, 0);             PUB(); MST(); FFN_MFMA(1, 0); PUB(); \
        STB(0, 1); VMW4();                PUB(); MST(); FFN_MFMA(1, 1); PUB(); \
        DSA(1, 0); DSB(1, 0); STA(0, 0);  PUB(); MST(); FFN_MFMA(0, 0); PUB(); \
        DSB(1, 1); STA(0, 1);             PUB(); MST(); FFN_MFMA(0, 1); PUB(); \
        DSA(1, 1); STB(1, 0);             PUB(); MST(); FFN_MFMA(1, 0); PUB(); \
        STB(1, 1); VMW4();                PUB(); MST(); FFN_MFMA(1, 1); PUB(); \
    } } while (0)

// ---------------- grouped GEMM1: h = gelu(x[tok] @ w1[e] + b1[e])  (fp16 out)
__global__ __launch_bounds__(512, 2) void k_ffn1(
    const u16* __restrict__ xh, const u16* __restrict__ w1t,
    const float* __restrict__ b1, u16* __restrict__ hbuf,
    const int* __restrict__ ctrl, const int* __restrict__ lists)
{
    extern __shared__ __align__(16) u16 lds[];
    u16* ldsA = lds;                   // [2][256*64]
    u16* ldsB = lds + 2 * 256 * 64;    // [2][256*64]
    const half8* HA = reinterpret_cast<const half8*>(ldsA);
    const half8* HB = reinterpret_cast<const half8*>(ldsB);
    int nwg = gridDim.x * gridDim.y;                   // 71*16=1136, %8==0
    int lid = blockIdx.y * gridDim.x + blockIdx.x;
    int sl = (lid & 7) * (nwg >> 3) + (lid >> 3);      // XCD-chunked bijection
    int t = sl % gridDim.x;
    int by = sl / gridDim.x;
    if (t >= ctrl[0]) return;
    int e = ctrl[32 + t], rt = ctrl[32 + MAXT2 + t], prow = ctrl[16 + e];
    int n0 = by * 256;
    int tid = threadIdx.x, lane = tid & 63, wv = tid >> 6;
    int wm = wv >> 2, wn = wv & 3;
    int lr = lane >> 3;
    int chunk = (lane & 7) ^ lr;                       // inverse-swizzled global src
    const int* lrow = lists + e * NTOK + rt * 256;
    const u16* pa[2][2]; const u16* pb[2][2];
#pragma unroll
    for (int h = 0; h < 2; ++h)
#pragma unroll
        for (int g = 0; g < 2; ++g) {
            int r = h * 128 + wv * 16 + g * 8 + lr;
            int tok = lrow[r] >> 1;
            pa[h][g] = xh + (size_t)tok * CDIM + chunk * 8;
            pb[h][g] = w1t + (size_t)e * HDIM * CDIM + (size_t)(n0 + r) * CDIM + chunk * 8;
        }
    int aIdx0 = wm * 1024 + (lane & 15) * 8 + ((lane >> 4) ^ (lane & 7));
    int aIdx1 = wm * 1024 + (lane & 15) * 8 + (((lane >> 4) + 4) ^ (lane & 7));
    int bIdx0 = wn * 512 + (lane & 15) * 8 + ((lane >> 4) ^ (lane & 7));
    int bIdx1 = wn * 512 + (lane & 15) * 8 + (((lane >> 4) + 4) ^ (lane & 7));
    f32x4 acc[8][4];
#pragma unroll
    for (int m = 0; m < 8; ++m)
#pragma unroll
        for (int n = 0; n < 4; ++n) acc[m][n] = f32x4{0.f, 0.f, 0.f, 0.f};
    half8 af[4][2], bf[2][2][2];

    FFN_KLOOP(16);   // K = 1024 = 16 tiles of 64

    // epilogue: D row=(lane>>4)*4+j -> hbuf col; D col=lane&15 -> token row
    const f32x4* b1v = reinterpret_cast<const f32x4*>(b1 + (size_t)e * HDIM);
    f32x4 bv[4];
#pragma unroll
    for (int n = 0; n < 4; ++n)
        bv[n] = b1v[(n0 + wn * 64 + n * 16) / 4 + (lane >> 4)];
#pragma unroll
    for (int m = 0; m < 8; ++m) {
        int grow = prow + rt * 256 + wm * 128 + m * 16 + (lane & 15);
        u16* hr = hbuf + (size_t)grow * HDIM + n0 + wn * 64 + (lane >> 4) * 4;
#pragma unroll
        for (int n = 0; n < 4; ++n) {
            ushort4 o;
#pragma unroll
            for (int j = 0; j < 4; ++j)
                ((u16*)&o)[j] = f2h(gelu_f(acc[m][n][j] + bv[n][j]));
            *reinterpret_cast<ushort4*>(hr + n * 16) = o;
        }
    }
}

// ---------------- grouped GEMM2 (K-split x2): y = (h @ w2[e] [+ b2]) * gate_w
__global__ __launch_bounds__(512, 2) void k_ffn2(
    const u16* __restrict__ hbuf, const u16* __restrict__ w2t,
    const float* __restrict__ b2, float* __restrict__ ybuf,
    const int* __restrict__ ctrl, const int* __restrict__ ptok,
    const float* __restrict__ pw)
{
    extern __shared__ __align__(16) u16 lds[];
    u16* ldsA = lds;
    u16* ldsB = lds + 2 * 256 * 64;
    const half8* HA = reinterpret_cast<const half8*>(ldsA);
    const half8* HB = reinterpret_cast<const half8*>(ldsB);
    int nwg = gridDim.x * gridDim.y * gridDim.z;       // 71*4*2=568, %8==0
    int lid = ((int)blockIdx.z * gridDim.y + blockIdx.y) * gridDim.x + blockIdx.x;
    int sl = (lid & 7) * (nwg >> 3) + (lid >> 3);
    int t = sl % gridDim.x;
    int r2 = sl / gridDim.x;
    int by = r2 & 3, kh = r2 >> 2;
    if (t >= ctrl[0]) return;
    int e = ctrl[32 + t], rt = ctrl[32 + MAXT2 + t], prow = ctrl[16 + e];
    int n0 = by * 256;
    int tid = threadIdx.x, lane = tid & 63, wv = tid >> 6;
    int wm = wv >> 2, wn = wv & 3;
    int lr = lane >> 3;
    int chunk = (lane & 7) ^ lr;
    int rowbase = prow + rt * 256;
    const u16* pa[2][2]; const u16* pb[2][2];
#pragma unroll
    for (int h = 0; h < 2; ++h)
#pragma unroll
        for (int g = 0; g < 2; ++g) {
            int r = h * 128 + wv * 16 + g * 8 + lr;
            pa[h][g] = hbuf + (size_t)(rowbase + r) * HDIM + kh * 2048 + chunk * 8;
            pb[h][g] = w2t + (size_t)e * CDIM * HDIM + (size_t)(n0 + r) * HDIM + kh * 2048 + chunk * 8;
        }
    int aIdx0 = wm * 1024 + (lane & 15) * 8 + ((lane >> 4) ^ (lane & 7));
    int aIdx1 = wm * 1024 + (lane & 15) * 8 + (((lane >> 4) + 4) ^ (lane & 7));
    int bIdx0 = wn * 512 + (lane & 15) * 8 + ((lane >> 4) ^ (lane & 7));
    int bIdx1 = wn * 512 + (lane & 15) * 8 + (((lane >> 4) + 4) ^ (lane & 7));
    f32x4 acc[8][4];
#pragma unroll
    for (int m = 0; m < 8; ++m)
#pragma unroll
        for (int n = 0; n < 4; ++n) acc[m][n] = f32x4{0.f, 0.f, 0.f, 0.f};
    half8 af[4][2], bf[2][2][2];

    FFN_KLOOP(32);   // K-half = 2048 = 32 tiles of 64

    int cnte = ctrl[8 + e];
    const f32x4* b2v = reinterpret_cast<const f32x4*>(b2 + (size_t)e * CDIM);
    f32x4 bv[4];
#pragma unroll
    for (int n = 0; n < 4; ++n)
        bv[n] = b2v[(n0 + wn * 64 + n * 16) / 4 + (lane >> 4)];
#pragma unroll
    for (int m = 0; m < 8; ++m) {
        int p = rt * 256 + wm * 128 + m * 16 + (lane & 15);
        bool valid = p < cnte;
        int g = prow + p;
        int entry = ptok[g];
        float wgt = pw[g];
        float* yb = ybuf + ((size_t)((entry & 1) * 2 + kh) * NTOK + (size_t)(entry >> 1)) * CDIM
                  + n0 + wn * 64 + (lane >> 4) * 4;
#pragma unroll
        for (int n = 0; n < 4; ++n) {
            f32x4 v = acc[m][n];
            if (kh == 0) v = v + bv[n];
            v = v * wgt;
            if (valid) *reinterpret_cast<f32x4*>(yb + n * 16) = v;
        }
    }
}

// ---------------- combine: out = sum of 4 ybuf slices (2 slots x 2 K-halves)
__global__ __launch_bounds__(256) void k_combine(
    const float* __restrict__ ybuf, float* __restrict__ out)
{
    size_t i = ((size_t)blockIdx.x * 256 + threadIdx.x) * 4;
    const size_t S = (size_t)NTOK * CDIM;
    f32x4 a = *reinterpret_cast<const f32x4*>(ybuf + i);
    f32x4 b = *reinterpret_cast<const f32x4*>(ybuf + S + i);
    f32x4 c = *reinterpret_cast<const f32x4*>(ybuf + 2 * S + i);
    f32x4 d = *reinterpret_cast<const f32x4*>(ybuf + 3 * S + i);
    *reinterpret_cast<f32x4*>(out + i) = (a + b) + (c + d);
}

extern "C" void kernel_launch(void* const* d_in, const int* in_sizes, int n_in,
                              void* d_out, int out_size, void* d_ws, size_t ws_size,
                              hipStream_t stream)
{
    const float* x  = (const float*)d_in[0];
    const float* gw = (const float*)d_in[1];
    const float* gb = (const float*)d_in[2];
    const float* w1 = (const float*)d_in[3];
    const float* b1 = (const float*)d_in[4];
    const float* w2 = (const float*)d_in[5];
    const float* b2 = (const float*)d_in[6];
    float* out = (float*)d_out;
    char* ws = (char*)d_ws;

    size_t off = 0;
    int*    ctrl  = (int*)(ws + off);    off += 4096;
    float2* rtw   = (float2*)(ws + off); off += (size_t)NTOK * 8;
    int*    ptok  = (int*)(ws + off);    off += (size_t)MAXROWS2 * 4;
    float*  pw    = (float*)(ws + off);  off += (size_t)MAXROWS2 * 4;
    int*    lists = (int*)(ws + off);    off += (size_t)NEXP * NTOK * 4;
    u16*    xh    = (u16*)(ws + off);    off += (size_t)NTOK * CDIM * 2;
    u16*    w1t   = (u16*)(ws + off);    off += (size_t)NEXP * CDIM * HDIM * 2;
    u16*    w2t   = (u16*)(ws + off);    off += (size_t)NEXP * CDIM * HDIM * 2;
    u16*    hbuf  = (u16*)(ws + off);    off += (size_t)MAXROWS2 * HDIM * 2;
    float*  ybuf  = (float*)(ws + off);  off += (size_t)4 * NTOK * CDIM * 4;
    (void)ws_size; (void)in_sizes; (void)n_in; (void)out_size;

    hipFuncSetAttribute((const void*)k_ffn1, hipFuncAttributeMaxDynamicSharedMemorySize, 131072);
    hipFuncSetAttribute((const void*)k_ffn2, hipFuncAttributeMaxDynamicSharedMemorySize, 131072);

    hipMemsetAsync(ctrl + 8, 0, NEXP * sizeof(int), stream);
    k_route<<<dim3(NTOK / 4), 256, 0, stream>>>(x, gw, gb, xh, rtw, ctrl + 8, lists);
    k_transpose<<<dim3(HDIM / 64, CDIM / 64, NEXP), 256, 0, stream>>>(w1, w1t, CDIM, HDIM);
    k_transpose<<<dim3(CDIM / 64, HDIM / 64, NEXP), 256, 0, stream>>>(w2, w2t, HDIM, CDIM);
    k_sched<<<dim3(1), 256, 0, stream>>>(ctrl, lists);
    k_pairs<<<dim3(64), 256, 0, stream>>>(ctrl, lists, rtw, ptok, pw);
    k_ffn1<<<dim3(MAXT2, HDIM / 256), 512, 131072, stream>>>(xh, w1t, b1, hbuf, ctrl, lists);
    k_ffn2<<<dim3(MAXT2, CDIM / 256, 2), 512, 131072, stream>>>(hbuf, w2t, b2, ybuf, ctrl, ptok, pw);
    k_combine<<<dim3(NTOK * CDIM / 1024), 256, 0, stream>>>(ybuf, out);
}

// Round 5
// 696.012 us; speedup vs baseline: 1.1944x; 1.0169x over previous
//
#include <hip/hip_runtime.h>
#include <math.h>

// MoE top-2/8: route -> grouped GEMM1 (gelu) -> grouped GEMM2 (scale, K-split) -> combine
// Shapes fixed: N=8192 tokens, C=1024, H=4096, E=8.
// FFN GEMMs: 256x256 tile, BK=64, 8 waves, 8-phase counted-vmcnt schedule (m201 template).
// R5: tile-major runtime-bijective XCD-chunked work mapping (A-panel L2 reuse;
//     dead blocks excluded from the bijection). FFN bodies unchanged from R4.

#define NTOK 8192
#define CDIM 1024
#define HDIM 4096
#define NEXP 8
#define MAXT2 71                   // worst-case sum over experts of ceil(cnt/256)
#define MAXROWS2 (MAXT2 * 256)

typedef unsigned short u16;
typedef __attribute__((ext_vector_type(8))) _Float16 half8;
typedef __attribute__((ext_vector_type(4))) float f32x4;

__device__ __forceinline__ u16 f2h(float f) {
    union { _Float16 h; u16 u; } cv; cv.h = (_Float16)f; return cv.u;
}
__device__ __forceinline__ void gll16(const u16* g, u16* l) {
    __builtin_amdgcn_global_load_lds((__attribute__((address_space(1))) void*)(g),
                                     (__attribute__((address_space(3))) void*)(l),
                                     16, 0, 0);
}
// exact-GELU via A&S 7.1.26 erf approx, |err(erf)| <= 1.5e-7
__device__ __forceinline__ float gelu_f(float v) {
    float u = 0.70710678118654752f * v;
    float au = fabsf(u);
    float t = __builtin_amdgcn_rcpf(1.0f + 0.3275911f * au);
    float p = t * (0.254829592f + t * (-0.284496736f + t * (1.421413741f +
              t * (-1.453152027f + t * 1.061405429f))));
    float ea = __expf(-au * au);
    float er = 1.0f - p * ea;
    er = (u < 0.f) ? -er : er;
    return 0.5f * v * (1.0f + er);
}
// bijective XCD-chunked remap over nact active blocks (m204): lid -> contiguous work id
__device__ __forceinline__ int xcd_remap(int lid, int nact) {
    int q = nact >> 3, r = nact & 7;
    int xcd = lid & 7, pos = lid >> 3;
    return (xcd < r) ? (xcd * (q + 1) + pos) : (r * (q + 1) + (xcd - r) * q + pos);
}

// ---------------- routing: gate logits, top-2 softmax, bucket append, x->fp16
__global__ __launch_bounds__(256) void k_route(
    const float* __restrict__ x, const float* __restrict__ gw,
    const float* __restrict__ gb, u16* __restrict__ xh,
    float2* __restrict__ rtw, int* __restrict__ cnt, int* __restrict__ lists)
{
    int tid = threadIdx.x, lane = tid & 63, wid = tid >> 6;
    int tok = blockIdx.x * 4 + wid;
    const float* xr = x + (size_t)tok * CDIM;
    float a[NEXP];
#pragma unroll
    for (int e = 0; e < NEXP; e++) a[e] = 0.f;
#pragma unroll
    for (int j = 0; j < 4; j++) {
        int k0 = j * 256 + lane * 4;
        float4 xv = *reinterpret_cast<const float4*>(xr + k0);
        ushort4 hv;
        hv.x = f2h(xv.x); hv.y = f2h(xv.y); hv.z = f2h(xv.z); hv.w = f2h(xv.w);
        *reinterpret_cast<ushort4*>(xh + (size_t)tok * CDIM + k0) = hv;
        const float* gr = gw + (size_t)k0 * NEXP;
#pragma unroll
        for (int t = 0; t < 4; t++) {
            float xs = (t == 0) ? xv.x : (t == 1) ? xv.y : (t == 2) ? xv.z : xv.w;
            float4 g0 = *reinterpret_cast<const float4*>(gr + t * 8);
            float4 g1 = *reinterpret_cast<const float4*>(gr + t * 8 + 4);
            a[0] += xs * g0.x; a[1] += xs * g0.y; a[2] += xs * g0.z; a[3] += xs * g0.w;
            a[4] += xs * g1.x; a[5] += xs * g1.y; a[6] += xs * g1.z; a[7] += xs * g1.w;
        }
    }
#pragma unroll
    for (int ofs = 32; ofs >= 1; ofs >>= 1) {
#pragma unroll
        for (int e = 0; e < NEXP; e++) a[e] += __shfl_xor(a[e], ofs, 64);
    }
    if (lane == 0) {
#pragma unroll
        for (int e = 0; e < NEXP; e++) a[e] += gb[e];
        int i0 = 0; float v0 = a[0];
#pragma unroll
        for (int e = 1; e < NEXP; e++) if (a[e] > v0) { v0 = a[e]; i0 = e; }
        int i1 = -1; float v1 = -3.4e38f;
#pragma unroll
        for (int e = 0; e < NEXP; e++) if (e != i0 && a[e] > v1) { v1 = a[e]; i1 = e; }
        float t = expf(v1 - v0);
        float w0 = 1.f / (1.f + t);
        rtw[tok] = make_float2(w0, t * w0);
        int p0 = atomicAdd(&cnt[i0], 1);
        lists[i0 * NTOK + p0] = tok * 2;
        int p1 = atomicAdd(&cnt[i1], 1);
        lists[i1 * NTOK + p1] = tok * 2 + 1;
    }
}

// ---------------- weight transpose+convert: [R][S] fp32 -> [S][R] fp16
__global__ __launch_bounds__(256) void k_transpose(
    const float* __restrict__ src, u16* __restrict__ dst, int R, int S)
{
    __shared__ __align__(16) u16 tile[64][68];
    int e = blockIdx.z;
    const float* se = src + (size_t)e * R * S;
    u16* de = dst + (size_t)e * R * S;
    int c0 = blockIdx.x * 64, r0 = blockIdx.y * 64;
    int tid = threadIdx.x;
    int rr = tid >> 4, cc = (tid & 15) * 4;
#pragma unroll
    for (int i = 0; i < 4; i++) {
        int r = rr + i * 16;
        float4 v = *reinterpret_cast<const float4*>(se + (size_t)(r0 + r) * S + c0 + cc);
        ushort4 hv; hv.x = f2h(v.x); hv.y = f2h(v.y); hv.z = f2h(v.z); hv.w = f2h(v.w);
        *reinterpret_cast<ushort4*>(&tile[r][cc]) = hv;
    }
    __syncthreads();
#pragma unroll
    for (int i = 0; i < 4; i++) {
        int row = rr + i * 16;
        ushort4 o;
        o.x = tile[cc + 0][row]; o.y = tile[cc + 1][row];
        o.z = tile[cc + 2][row]; o.w = tile[cc + 3][row];
        *reinterpret_cast<ushort4*>(de + (size_t)(c0 + row) * R + r0 + cc) = o;
    }
}

// ---------------- schedule: prefix sums, tile tables (256-granularity), pad lists
__global__ __launch_bounds__(256) void k_sched(
    int* __restrict__ ctrl, int* __restrict__ lists)
{
    __shared__ int scnt[NEXP], stile[NEXP], sstart[NEXP], stot;
    int tid = threadIdx.x;
    if (tid == 0) {
        int at = 0, ar = 0;
        for (int e = 0; e < NEXP; e++) {
            int c = ctrl[8 + e]; scnt[e] = c;
            int ti = (c + 255) >> 8;
            stile[e] = ti; sstart[e] = at;
            ctrl[16 + e] = ar;
            at += ti; ar += ti * 256;
        }
        stot = at; ctrl[0] = at; ctrl[1] = ar;
    }
    __syncthreads();
    for (int t = tid; t < stot; t += 256) {
        int e = 0;
        while (e < NEXP - 1 && t >= sstart[e] + stile[e]) e++;
        ctrl[32 + t] = e;
        ctrl[32 + MAXT2 + t] = t - sstart[e];
    }
    for (int e = 0; e < NEXP; e++) {
        int c = scnt[e], lim = stile[e] * 256;
        if (c > 0) {
            int fill = lists[e * NTOK];
            for (int p = c + tid; p < lim; p += 256) lists[e * NTOK + p] = fill;
        }
    }
}

// ---------------- pair arrays (parallel): ptok/pw for every padded row
__global__ __launch_bounds__(256) void k_pairs(
    const int* __restrict__ ctrl, const int* __restrict__ lists,
    const float2* __restrict__ rtw, int* __restrict__ ptok, float* __restrict__ pw)
{
    int tot = ctrl[1];
    for (int g = blockIdx.x * 256 + threadIdx.x; g < tot; g += gridDim.x * 256) {
        int e = 0;
#pragma unroll
        for (int q = 1; q < NEXP; q++) e = (g >= ctrl[16 + q]) ? q : e;
        int p = g - ctrl[16 + e];
        int entry = lists[e * NTOK + p];
        ptok[g] = entry;
        float2 w = rtw[entry >> 1];
        pw[g] = (entry & 1) ? w.y : w.x;
    }
}

// ======== 8-phase 256x256 GEMM engine (macros; use local names in scope) ========
// LDS: ldsA/ldsB = [2 bufs][256 rows][64 k] fp16 each (128KB total dynamic).
// Swizzle: 16B chunk slot' = slot ^ (row&7); staged via inverse-swizzled global src.
// All fragment reads are half8-typed (16B-aligned) -> ds_read_b128 offset:imm.
#define DSA(BUF, QR) do { \
    _Pragma("unroll") for (int fm_ = 0; fm_ < 4; ++fm_) { \
        af[fm_][0] = HA[aIdx0 + ((QR) * 4 + fm_) * 128 + (BUF) * 2048]; \
        af[fm_][1] = HA[aIdx1 + ((QR) * 4 + fm_) * 128 + (BUF) * 2048]; \
    } } while (0)

#define DSB(BUF, QC) do { \
    _Pragma("unroll") for (int fn_ = 0; fn_ < 2; ++fn_) { \
        bf[QC][fn_][0] = HB[bIdx0 + ((QC) * 2 + fn_) * 128 + (BUF) * 2048]; \
        bf[QC][fn_][1] = HB[bIdx1 + ((QC) * 2 + fn_) * 128 + (BUF) * 2048]; \
    } } while (0)

#define FFN_MFMA(QR, QC) do { \
    __builtin_amdgcn_s_setprio(1); \
    _Pragma("unroll") for (int fm_ = 0; fm_ < 4; ++fm_) \
    _Pragma("unroll") for (int fn_ = 0; fn_ < 2; ++fn_) { \
        acc[(QR) * 4 + fm_][(QC) * 2 + fn_] = __builtin_amdgcn_mfma_f32_16x16x32_f16( \
            bf[QC][fn_][0], af[fm_][0], acc[(QR) * 4 + fm_][(QC) * 2 + fn_], 0, 0, 0); \
        acc[(QR) * 4 + fm_][(QC) * 2 + fn_] = __builtin_amdgcn_mfma_f32_16x16x32_f16( \
            bf[QC][fn_][1], af[fm_][1], acc[(QR) * 4 + fm_][(QC) * 2 + fn_], 0, 0, 0); \
    } \
    __builtin_amdgcn_s_setprio(0); } while (0)

#define PUB() do { __builtin_amdgcn_sched_barrier(0); __builtin_amdgcn_s_barrier(); } while (0)
#define MST() do { asm volatile("s_waitcnt lgkmcnt(0)" ::: "memory"); \
                   __builtin_amdgcn_sched_barrier(0); } while (0)
#define VMW4() asm volatile("s_waitcnt vmcnt(4)" ::: "memory")

#define STA(BUF, H) do { \
    gll16(pa[H][0], ldsA + (BUF) * 16384 + ((H) * 128 + wv * 16) * 64); pa[H][0] += 64; \
    gll16(pa[H][1], ldsA + (BUF) * 16384 + ((H) * 128 + wv * 16 + 8) * 64); pa[H][1] += 64; } while (0)

#define STB(BUF, H) do { \
    gll16(pb[H][0], ldsB + (BUF) * 16384 + ((H) * 128 + wv * 16) * 64); pb[H][0] += 64; \
    gll16(pb[H][1], ldsB + (BUF) * 16384 + ((H) * 128 + wv * 16 + 8) * 64); pb[H][1] += 64; } while (0)

// per iteration: tiles (2i)->buf0, (2i+1)->buf1; stage A(2i+1),B(2i+2),A(2i+2),B(2i+3).
#define FFN_KLOOP(NK) do { \
    STB(0, 0); STB(0, 1); STA(0, 0); STA(0, 1); STB(1, 0); STB(1, 1); \
    VMW4(); PUB(); \
    for (int i_ = 0; i_ < (NK) / 2; ++i_) { \
        DSA(0, 0); DSB(0, 0); STA(1, 0);  PUB(); MST(); FFN_MFMA(0, 0); PUB(); \
        DSB(0, 1); STA(1, 1);             PUB(); MST(); FFN_MFMA(0, 1); PUB(); \
        DSA(0, 1); STB(0, 0);             PUB(); MST(); FFN_MFMA(1, 0); PUB(); \
        STB(0, 1); VMW4();                PUB(); MST(); FFN_MFMA(1, 1); PUB(); \
        DSA(1, 0); DSB(1, 0); STA(0, 0);  PUB(); MST(); FFN_MFMA(0, 0); PUB(); \
        DSB(1, 1); STA(0, 1);             PUB(); MST(); FFN_MFMA(0, 1); PUB(); \
        DSA(1, 1); STB(1, 0);             PUB(); MST(); FFN_MFMA(1, 0); PUB(); \
        STB(1, 1); VMW4();                PUB(); MST(); FFN_MFMA(1, 1); PUB(); \
    } } while (0)

// ---------------- grouped GEMM1: h = gelu(x[tok] @ w1[e] + b1[e])  (fp16 out)
__global__ __launch_bounds__(512, 2) void k_ffn1(
    const u16* __restrict__ xh, const u16* __restrict__ w1t,
    const float* __restrict__ b1, u16* __restrict__ hbuf,
    const int* __restrict__ ctrl, const int* __restrict__ lists)
{
    extern __shared__ __align__(16) u16 lds[];
    u16* ldsA = lds;                   // [2][256*64]
    u16* ldsB = lds + 2 * 256 * 64;    // [2][256*64]
    const half8* HA = reinterpret_cast<const half8*>(ldsA);
    const half8* HB = reinterpret_cast<const half8*>(ldsB);
    int lid = blockIdx.y * gridDim.x + blockIdx.x;
    int nact = ctrl[0] * 16;                           // active blocks
    if (lid >= nact) return;
    int w = xcd_remap(lid, nact);                      // tile-major: by fastest
    int t = w >> 4;
    int by = w & 15;
    int e = ctrl[32 + t], rt = ctrl[32 + MAXT2 + t], prow = ctrl[16 + e];
    int n0 = by * 256;
    int tid = threadIdx.x, lane = tid & 63, wv = tid >> 6;
    int wm = wv >> 2, wn = wv & 3;
    int lr = lane >> 3;
    int chunk = (lane & 7) ^ lr;                       // inverse-swizzled global src
    const int* lrow = lists + e * NTOK + rt * 256;
    const u16* pa[2][2]; const u16* pb[2][2];
#pragma unroll
    for (int h = 0; h < 2; ++h)
#pragma unroll
        for (int g = 0; g < 2; ++g) {
            int r = h * 128 + wv * 16 + g * 8 + lr;
            int tok = lrow[r] >> 1;
            pa[h][g] = xh + (size_t)tok * CDIM + chunk * 8;
            pb[h][g] = w1t + (size_t)e * HDIM * CDIM + (size_t)(n0 + r) * CDIM + chunk * 8;
        }
    int aIdx0 = wm * 1024 + (lane & 15) * 8 + ((lane >> 4) ^ (lane & 7));
    int aIdx1 = wm * 1024 + (lane & 15) * 8 + (((lane >> 4) + 4) ^ (lane & 7));
    int bIdx0 = wn * 512 + (lane & 15) * 8 + ((lane >> 4) ^ (lane & 7));
    int bIdx1 = wn * 512 + (lane & 15) * 8 + (((lane >> 4) + 4) ^ (lane & 7));
    f32x4 acc[8][4];
#pragma unroll
    for (int m = 0; m < 8; ++m)
#pragma unroll
        for (int n = 0; n < 4; ++n) acc[m][n] = f32x4{0.f, 0.f, 0.f, 0.f};
    half8 af[4][2], bf[2][2][2];

    FFN_KLOOP(16);   // K = 1024 = 16 tiles of 64

    // epilogue: D row=(lane>>4)*4+j -> hbuf col; D col=lane&15 -> token row
    const f32x4* b1v = reinterpret_cast<const f32x4*>(b1 + (size_t)e * HDIM);
    f32x4 bv[4];
#pragma unroll
    for (int n = 0; n < 4; ++n)
        bv[n] = b1v[(n0 + wn * 64 + n * 16) / 4 + (lane >> 4)];
#pragma unroll
    for (int m = 0; m < 8; ++m) {
        int grow = prow + rt * 256 + wm * 128 + m * 16 + (lane & 15);
        u16* hr = hbuf + (size_t)grow * HDIM + n0 + wn * 64 + (lane >> 4) * 4;
#pragma unroll
        for (int n = 0; n < 4; ++n) {
            ushort4 o;
#pragma unroll
            for (int j = 0; j < 4; ++j)
                ((u16*)&o)[j] = f2h(gelu_f(acc[m][n][j] + bv[n][j]));
            *reinterpret_cast<ushort4*>(hr + n * 16) = o;
        }
    }
}

// ---------------- grouped GEMM2 (K-split x2): y = (h @ w2[e] [+ b2]) * gate_w
__global__ __launch_bounds__(512, 2) void k_ffn2(
    const u16* __restrict__ hbuf, const u16* __restrict__ w2t,
    const float* __restrict__ b2, float* __restrict__ ybuf,
    const int* __restrict__ ctrl, const int* __restrict__ ptok,
    const float* __restrict__ pw)
{
    extern __shared__ __align__(16) u16 lds[];
    u16* ldsA = lds;
    u16* ldsB = lds + 2 * 256 * 64;
    const half8* HA = reinterpret_cast<const half8*>(ldsA);
    const half8* HB = reinterpret_cast<const half8*>(ldsB);
    int lid = ((int)blockIdx.z * gridDim.y + blockIdx.y) * gridDim.x + blockIdx.x;
    int nact = ctrl[0] * 8;                            // tiles * 4 by * 2 kh
    if (lid >= nact) return;
    int w = xcd_remap(lid, nact);                      // tile-major: kh then by fastest
    int t = w >> 3;
    int kh = (w >> 2) & 1;
    int by = w & 3;
    int e = ctrl[32 + t], rt = ctrl[32 + MAXT2 + t], prow = ctrl[16 + e];
    int n0 = by * 256;
    int tid = threadIdx.x, lane = tid & 63, wv = tid >> 6;
    int wm = wv >> 2, wn = wv & 3;
    int lr = lane >> 3;
    int chunk = (lane & 7) ^ lr;
    int rowbase = prow + rt * 256;
    const u16* pa[2][2]; const u16* pb[2][2];
#pragma unroll
    for (int h = 0; h < 2; ++h)
#pragma unroll
        for (int g = 0; g < 2; ++g) {
            int r = h * 128 + wv * 16 + g * 8 + lr;
            pa[h][g] = hbuf + (size_t)(rowbase + r) * HDIM + kh * 2048 + chunk * 8;
            pb[h][g] = w2t + (size_t)e * CDIM * HDIM + (size_t)(n0 + r) * HDIM + kh * 2048 + chunk * 8;
        }
    int aIdx0 = wm * 1024 + (lane & 15) * 8 + ((lane >> 4) ^ (lane & 7));
    int aIdx1 = wm * 1024 + (lane & 15) * 8 + (((lane >> 4) + 4) ^ (lane & 7));
    int bIdx0 = wn * 512 + (lane & 15) * 8 + ((lane >> 4) ^ (lane & 7));
    int bIdx1 = wn * 512 + (lane & 15) * 8 + (((lane >> 4) + 4) ^ (lane & 7));
    f32x4 acc[8][4];
#pragma unroll
    for (int m = 0; m < 8; ++m)
#pragma unroll
        for (int n = 0; n < 4; ++n) acc[m][n] = f32x4{0.f, 0.f, 0.f, 0.f};
    half8 af[4][2], bf[2][2][2];

    FFN_KLOOP(32);   // K-half = 2048 = 32 tiles of 64

    int cnte = ctrl[8 + e];
    const f32x4* b2v = reinterpret_cast<const f32x4*>(b2 + (size_t)e * CDIM);
    f32x4 bv[4];
#pragma unroll
    for (int n = 0; n < 4; ++n)
        bv[n] = b2v[(n0 + wn * 64 + n * 16) / 4 + (lane >> 4)];
#pragma unroll
    for (int m = 0; m < 8; ++m) {
        int p = rt * 256 + wm * 128 + m * 16 + (lane & 15);
        bool valid = p < cnte;
        int g = prow + p;
        int entry = ptok[g];
        float wgt = pw[g];
        float* yb = ybuf + ((size_t)((entry & 1) * 2 + kh) * NTOK + (size_t)(entry >> 1)) * CDIM
                  + n0 + wn * 64 + (lane >> 4) * 4;
#pragma unroll
        for (int n = 0; n < 4; ++n) {
            f32x4 v = acc[m][n];
            if (kh == 0) v = v + bv[n];
            v = v * wgt;
            if (valid) *reinterpret_cast<f32x4*>(yb + n * 16) = v;
        }
    }
}

// ---------------- combine: out = sum of 4 ybuf slices (2 slots x 2 K-halves)
__global__ __launch_bounds__(256) void k_combine(
    const float* __restrict__ ybuf, float* __restrict__ out)
{
    size_t i = ((size_t)blockIdx.x * 256 + threadIdx.x) * 4;
    const size_t S = (size_t)NTOK * CDIM;
    f32x4 a = *reinterpret_cast<const f32x4*>(ybuf + i);
    f32x4 b = *reinterpret_cast<const f32x4*>(ybuf + S + i);
    f32x4 c = *reinterpret_cast<const f32x4*>(ybuf + 2 * S + i);
    f32x4 d = *reinterpret_cast<const f32x4*>(ybuf + 3 * S + i);
    *reinterpret_cast<f32x4*>(out + i) = (a + b) + (c + d);
}

extern "C" void kernel_launch(void* const* d_in, const int* in_sizes, int n_in,
                              void* d_out, int out_size, void* d_ws, size_t ws_size,
                              hipStream_t stream)
{
    const float* x  = (const float*)d_in[0];
    const float* gw = (const float*)d_in[1];
    const float* gb = (const float*)d_in[2];
    const float* w1 = (const float*)d_in[3];
    const float* b1 = (const float*)d_in[4];
    const float* w2 = (const float*)d_in[5];
    const float* b2 = (const float*)d_in[6];
    float* out = (float*)d_out;
    char* ws = (char*)d_ws;

    size_t off = 0;
    int*    ctrl  = (int*)(ws + off);    off += 4096;
    float2* rtw   = (float2*)(ws + off); off += (size_t)NTOK * 8;
    int*    ptok  = (int*)(ws + off);    off += (size_t)MAXROWS2 * 4;
    float*  pw    = (float*)(ws + off);  off += (size_t)MAXROWS2 * 4;
    int*    lists = (int*)(ws + off);    off += (size_t)NEXP * NTOK * 4;
    u16*    xh    = (u16*)(ws + off);    off += (size_t)NTOK * CDIM * 2;
    u16*    w1t   = (u16*)(ws + off);    off += (size_t)NEXP * CDIM * HDIM * 2;
    u16*    w2t   = (u16*)(ws + off);    off += (size_t)NEXP * CDIM * HDIM * 2;
    u16*    hbuf  = (u16*)(ws + off);    off += (size_t)MAXROWS2 * HDIM * 2;
    float*  ybuf  = (float*)(ws + off);  off += (size_t)4 * NTOK * CDIM * 4;
    (void)ws_size; (void)in_sizes; (void)n_in; (void)out_size;

    hipFuncSetAttribute((const void*)k_ffn1, hipFuncAttributeMaxDynamicSharedMemorySize, 131072);
    hipFuncSetAttribute((const void*)k_ffn2, hipFuncAttributeMaxDynamicSharedMemorySize, 131072);

    hipMemsetAsync(ctrl + 8, 0, NEXP * sizeof(int), stream);
    k_route<<<dim3(NTOK / 4), 256, 0, stream>>>(x, gw, gb, xh, rtw, ctrl + 8, lists);
    k_transpose<<<dim3(HDIM / 64, CDIM / 64, NEXP), 256, 0, stream>>>(w1, w1t, CDIM, HDIM);
    k_transpose<<<dim3(CDIM / 64, HDIM / 64, NEXP), 256, 0, stream>>>(w2, w2t, HDIM, CDIM);
    k_sched<<<dim3(1), 256, 0, stream>>>(ctrl, lists);
    k_pairs<<<dim3(64), 256, 0, stream>>>(ctrl, lists, rtw, ptok, pw);
    k_ffn1<<<dim3(MAXT2, HDIM / 256), 512, 131072, stream>>>(xh, w1t, b1, hbuf, ctrl, lists);
    k_ffn2<<<dim3(MAXT2, CDIM / 256, 2), 512, 131072, stream>>>(hbuf, w2t, b2, ybuf, ctrl, ptok, pw);
    k_combine<<<dim3(NTOK * CDIM / 1024), 256, 0, stream>>>(ybuf, out);
}